// Round 4
// baseline (489.951 us; speedup 1.0000x reference)
//
#include <hip/hip_runtime.h>
#include <hip/hip_bf16.h>

typedef _Float16 half8  __attribute__((ext_vector_type(8)));
typedef _Float16 half4v __attribute__((ext_vector_type(4)));
typedef float    f32x4  __attribute__((ext_vector_type(4)));

#define N_NODES 100000
#define N_EDGES 3200000
#define SH_STRIDE 100096   // shadow stride (floats), 128B-aligned

// ---------------------------------------------------------------------------
// Pack all 7 fp32 weights [256][K+pad] -> fp16 [256][K]; concat-edge column
// -> fp32 we[6*256].
// ---------------------------------------------------------------------------
__global__ void pack_all(const float* __restrict__ W1,  const float* __restrict__ Wm1,
                         const float* __restrict__ Wm2, const float* __restrict__ Wm3,
                         const float* __restrict__ Wm4, const float* __restrict__ Wr1,
                         const float* __restrict__ Wr2,
                         _Float16* __restrict__ dst, float* __restrict__ we) {
    const float* srcs[7] = {W1, Wm1, Wm2, Wm3, Wm4, Wr1, Wr2};
    const int gid = blockIdx.x * blockDim.x + threadIdx.x;
    const int gsz = gridDim.x * blockDim.x;
    for (int i = gid; i < 425984; i += gsz) {
        int job, row, k, stride;
        if (i < 32768) { job = 0; row = i >> 7; k = i & 127; stride = 129; }
        else {
            int t = i - 32768; job = 1 + (t >> 16); int w = t & 65535;
            row = w >> 8; k = w & 255; stride = (job == 6) ? 256 : 257;
        }
        dst[i] = (_Float16)srcs[job][row * stride + k];
    }
    for (int i = gid; i < 1536; i += gsz) {
        const int job = i >> 8, row = i & 255;
        const int stride = (job == 0) ? 129 : 257;
        const int kin    = (job == 0) ? 128 : 256;
        we[i] = srcs[job][row * stride + kin];
    }
}

// ---------------------------------------------------------------------------
// XCD-local scatter: shadow pair selected by HW_REG_XCC_ID (m09-verified on
// gfx950); workgroup-scope atomics execute at the XCD's own L2 -> no
// cross-XCD coherence traffic. Visibility to the next kernel comes from the
// end-of-dispatch L2 writeback the runtime performs between dependent
// dispatches (required for plain stores too).
// ---------------------------------------------------------------------------
__global__ void scatter16(const float4* __restrict__ ef4,
                          const int4* __restrict__ dst4,
                          float* __restrict__ e) {
    unsigned xcc;
    asm volatile("s_getreg_b32 %0, hwreg(HW_REG_XCC_ID)" : "=s"(xcc));
    float* __restrict__ b0 = e + (size_t)(xcc * 2) * SH_STRIDE;
    float* __restrict__ b1 = b0 + SH_STRIDE;
    const int n4 = N_EDGES / 4;
    for (int i = blockIdx.x * blockDim.x + threadIdx.x; i < n4;
         i += gridDim.x * blockDim.x) {
        const float4 f = ef4[i];
        const int4   d = dst4[i];
        __hip_atomic_fetch_add(&b0[d.x], f.x, __ATOMIC_RELAXED, __HIP_MEMORY_SCOPE_WORKGROUP);
        __hip_atomic_fetch_add(&b1[d.y], f.y, __ATOMIC_RELAXED, __HIP_MEMORY_SCOPE_WORKGROUP);
        __hip_atomic_fetch_add(&b0[d.z], f.z, __ATOMIC_RELAXED, __HIP_MEMORY_SCOPE_WORKGROUP);
        __hip_atomic_fetch_add(&b1[d.w], f.w, __ATOMIC_RELAXED, __HIP_MEMORY_SCOPE_WORKGROUP);
    }
}

// fallback: device-scope split-4 (known-good R3 path)
__global__ void scatter4(const float4* __restrict__ ef4,
                         const int4* __restrict__ dst4,
                         float* __restrict__ e) {
    const int n4 = N_EDGES / 4;
    for (int i = blockIdx.x * blockDim.x + threadIdx.x; i < n4;
         i += gridDim.x * blockDim.x) {
        const float4 f = ef4[i];
        const int4   d = dst4[i];
        atomicAdd(&e[d.x], f.x);
        atomicAdd(&e[SH_STRIDE + d.y], f.y);
        atomicAdd(&e[2 * SH_STRIDE + d.z], f.z);
        atomicAdd(&e[3 * SH_STRIDE + d.w], f.w);
    }
}

// ---------------------------------------------------------------------------
// One layer over a 128-node tile, 4 waves. Wave (rowhalf, colhalf) owns
// 64 nodes x 128 output cols: acc[jt=8][mt=4]. Each 16B H b-frag (ds_read)
// feeds 8 MFMAs -> LDS pipe (CU-shared) balanced against MFMA pipes (4x).
// a-frag = W rows from global (L1/L2-cached, 2 ksteps per 128B line).
// D: col=lane&15 -> node, row=quad*4+r -> 4 consecutive out features -> 8B
// packed LDS stores, conflict-free phase pattern.
// ---------------------------------------------------------------------------
template<int K>
__device__ __forceinline__ void layer_mm(const _Float16* __restrict__ Wl,
                                         _Float16 (* __restrict__ Hs)[264],
                                         const float* __restrict__ es,
                                         const float* __restrict__ wes,
                                         const float* __restrict__ bs,
                                         int colhalf, int rowhalf,
                                         int m_, int quad) {
    f32x4 acc[8][4];
    #pragma unroll
    for (int jt = 0; jt < 8; ++jt)
        #pragma unroll
        for (int mt = 0; mt < 4; ++mt)
            acc[jt][mt] = (f32x4){0.f, 0.f, 0.f, 0.f};

    const _Float16* __restrict__ wp =
        Wl + (size_t)(colhalf * 128 + m_) * K + quad * 8;

    #pragma unroll
    for (int kk = 0; kk < K; kk += 32) {
        half8 a[8], b[4];
        #pragma unroll
        for (int jt = 0; jt < 8; ++jt)
            a[jt] = *(const half8*)(wp + (size_t)jt * 16 * K + kk);
        #pragma unroll
        for (int mt = 0; mt < 4; ++mt)
            b[mt] = *(const half8*)&Hs[rowhalf * 64 + mt * 16 + m_][kk + quad * 8];
        #pragma unroll
        for (int jt = 0; jt < 8; ++jt)
            #pragma unroll
            for (int mt = 0; mt < 4; ++mt)
                acc[jt][mt] = __builtin_amdgcn_mfma_f32_16x16x32_f16(
                    a[jt], b[mt], acc[jt][mt], 0, 0, 0);
    }
    __syncthreads();   // all waves done reading Hs; wes/bs ready

    #pragma unroll
    for (int jt = 0; jt < 8; ++jt) {
        const int jbase = colhalf * 128 + jt * 16 + quad * 4;
        const float4 we4 = *(const float4*)&wes[jbase];
        const float4 bb4 = *(const float4*)&bs[jbase];
        #pragma unroll
        for (int mt = 0; mt < 4; ++mt) {
            const int node = rowhalf * 64 + mt * 16 + m_;
            const float ev = es[node];
            half4v h;
            h[0] = (_Float16)fmaxf(acc[jt][mt][0] + ev * we4.x + bb4.x, 0.f);
            h[1] = (_Float16)fmaxf(acc[jt][mt][1] + ev * we4.y + bb4.y, 0.f);
            h[2] = (_Float16)fmaxf(acc[jt][mt][2] + ev * we4.z + bb4.z, 0.f);
            h[3] = (_Float16)fmaxf(acc[jt][mt][3] + ev * we4.w + bb4.w, 0.f);
            *(half4v*)&Hs[node][jbase] = h;
        }
    }
    __syncthreads();   // Hs complete before next layer / wes overwrite
}

// ---------------------------------------------------------------------------
__global__ __launch_bounds__(256, 2) void sage_fused(
    const float* __restrict__ node_feat, const float* __restrict__ esh,
    int nsh,
    const _Float16* __restrict__ Wpack, const float* __restrict__ wepack,
    const float* __restrict__ b1, const float* __restrict__ bm1,
    const float* __restrict__ bm2, const float* __restrict__ bm3,
    const float* __restrict__ bm4, const float* __restrict__ br1,
    const float* __restrict__ br2, const float* __restrict__ wr3,
    const float* __restrict__ br3, float* __restrict__ out) {

    __shared__ _Float16 Hs[128][264];   // +8-half pad
    __shared__ float es[128];
    __shared__ float wes[256];
    __shared__ float bs[256];
    __shared__ float red[2][128];

    const int tid  = threadIdx.x;
    const int wave = tid >> 6;
    const int lane = tid & 63;
    const int m_   = lane & 15;
    const int quad = lane >> 4;
    const int colhalf = wave & 1;
    const int rowhalf = wave >> 1;
    const int node0 = blockIdx.x * 128;

    // ---- stage node_feat tile (fp32 -> fp16), cols [0,128) ----
    for (int idx = tid; idx < 128 * 16; idx += 256) {
        const int row = idx >> 4, g = idx & 15;
        int node = node0 + row; if (node >= N_NODES) node = N_NODES - 1;
        const float4* src = (const float4*)(node_feat + (size_t)node * 128 + g * 8);
        const float4 v0 = src[0], v1 = src[1];
        half8 h;
        h[0] = (_Float16)v0.x; h[1] = (_Float16)v0.y;
        h[2] = (_Float16)v0.z; h[3] = (_Float16)v0.w;
        h[4] = (_Float16)v1.x; h[5] = (_Float16)v1.y;
        h[6] = (_Float16)v1.z; h[7] = (_Float16)v1.w;
        *(half8*)&Hs[row][g * 8] = h;
    }
    if (tid < 128) {
        int node = node0 + tid; if (node >= N_NODES) node = N_NODES - 1;
        float s = 0.f;
        for (int sh = 0; sh < nsh; ++sh) s += esh[(size_t)sh * SH_STRIDE + node];
        es[tid] = s;
    }
    __syncthreads();

    const float* b_l[7] = {b1, bm1, bm2, bm3, bm4, br1, br2};

    // layer 0: K=128
    wes[tid] = wepack[tid];
    bs[tid]  = b1[tid];
    layer_mm<128>(Wpack, Hs, es, wes, bs, colhalf, rowhalf, m_, quad);

    // layers 1..6: K=256
    for (int l = 1; l < 7; ++l) {
        wes[tid] = (l < 6) ? wepack[l * 256 + tid] : 0.f;
        bs[tid]  = b_l[l][tid];
        layer_mm<256>(Wpack + 32768 + (l - 1) * 65536, Hs, es, wes, bs,
                      colhalf, rowhalf, m_, quad);
    }

    // ---- final 256 -> 1 dot (fp32) ----
    wes[tid] = wr3[tid];
    __syncthreads();
    {
        const int row = tid & 127, seg = tid >> 7;
        const _Float16* hp = &Hs[row][seg * 128];
        const float* wp = &wes[seg * 128];
        float s = 0.f;
        #pragma unroll 8
        for (int k = 0; k < 128; ++k) s += (float)hp[k] * wp[k];
        red[seg][row] = s;
    }
    __syncthreads();
    if (tid < 128) {
        const int node = node0 + tid;
        if (node < N_NODES)
            out[node] = red[0][tid] + red[1][tid] + br3[0];
    }
}

// ---------------------------------------------------------------------------
extern "C" void kernel_launch(void* const* d_in, const int* in_sizes, int n_in,
                              void* d_out, int out_size, void* d_ws,
                              size_t ws_size, hipStream_t stream) {
    const float* node_feat = (const float*)d_in[0];
    const float* edge_feat = (const float*)d_in[1];
    const int*   edge_dst  = (const int*)d_in[2];
    const float* W1  = (const float*)d_in[3];  const float* b1  = (const float*)d_in[4];
    const float* Wm1 = (const float*)d_in[5];  const float* bm1 = (const float*)d_in[6];
    const float* Wm2 = (const float*)d_in[7];  const float* bm2 = (const float*)d_in[8];
    const float* Wm3 = (const float*)d_in[9];  const float* bm3 = (const float*)d_in[10];
    const float* Wm4 = (const float*)d_in[11]; const float* bm4 = (const float*)d_in[12];
    const float* Wr1 = (const float*)d_in[13]; const float* br1 = (const float*)d_in[14];
    const float* Wr2 = (const float*)d_in[15]; const float* br2 = (const float*)d_in[16];
    const float* Wr3 = (const float*)d_in[17]; const float* br3 = (const float*)d_in[18];
    float* out = (float*)d_out;

    // workspace layout: Wp | wep | shadows
    char* ws = (char*)d_ws;
    _Float16* Wp  = (_Float16*)ws;                       // 851968 B
    float*    wep = (float*)(ws + 851968);               // 6144 B
    float*    esh = (float*)(ws + 858112);               // nsh * 400384 B

    const size_t need16 = 858112 + (size_t)16 * SH_STRIDE * 4;
    const int nsh = (ws_size >= need16) ? 16 : 4;

    hipMemsetAsync(esh, 0, (size_t)nsh * SH_STRIDE * 4, stream);

    if (nsh == 16)
        scatter16<<<3125, 256, 0, stream>>>((const float4*)edge_feat,
                                            (const int4*)edge_dst, esh);
    else
        scatter4<<<3125, 256, 0, stream>>>((const float4*)edge_feat,
                                           (const int4*)edge_dst, esh);

    pack_all<<<1664, 256, 0, stream>>>(W1, Wm1, Wm2, Wm3, Wm4, Wr1, Wr2,
                                       Wp, wep);

    const int nblk = (N_NODES + 127) / 128;   // 782
    sage_fused<<<nblk, 256, 0, stream>>>(node_feat, esh, nsh, Wp, wep,
                                         b1, bm1, bm2, bm3, bm4, br1, br2,
                                         Wr3, br3, out);
}

// Round 5
// 353.657 us; speedup vs baseline: 1.3854x; 1.3854x over previous
//
#include <hip/hip_runtime.h>
#include <hip/hip_bf16.h>

typedef _Float16 half8  __attribute__((ext_vector_type(8)));
typedef _Float16 half4v __attribute__((ext_vector_type(4)));
typedef float    f32x4  __attribute__((ext_vector_type(4)));

#define N_NODES 100000
#define N_EDGES 3200000
#define SH_STRIDE 100096   // fallback shadow stride (floats)
#define NBUCK 782          // ceil(N_NODES/128) — one bucket per sage tile
#define CAP 5120           // pairs per bucket; mean 4096, +16 sigma pad
#define CHUNK 16384        // edges per bin_edges block

// ---------------------------------------------------------------------------
// Pack all 7 fp32 weights [256][K+pad] -> fp16 [256][K]; concat-edge column
// -> fp32 we[6*256]; init per-bucket cursors to b*CAP.
// ---------------------------------------------------------------------------
__global__ void pack_all(const float* __restrict__ W1,  const float* __restrict__ Wm1,
                         const float* __restrict__ Wm2, const float* __restrict__ Wm3,
                         const float* __restrict__ Wm4, const float* __restrict__ Wr1,
                         const float* __restrict__ Wr2,
                         _Float16* __restrict__ dst, float* __restrict__ we,
                         int* __restrict__ cursor) {
    const float* srcs[7] = {W1, Wm1, Wm2, Wm3, Wm4, Wr1, Wr2};
    const int gid = blockIdx.x * blockDim.x + threadIdx.x;
    const int gsz = gridDim.x * blockDim.x;
    for (int i = gid; i < 425984; i += gsz) {
        int job, row, k, stride;
        if (i < 32768) { job = 0; row = i >> 7; k = i & 127; stride = 129; }
        else {
            int t = i - 32768; job = 1 + (t >> 16); int w = t & 65535;
            row = w >> 8; k = w & 255; stride = (job == 6) ? 256 : 257;
        }
        dst[i] = (_Float16)srcs[job][row * stride + k];
    }
    for (int i = gid; i < 1536; i += gsz) {
        const int job = i >> 8, row = i & 255;
        const int stride = (job == 0) ? 129 : 257;
        const int kin    = (job == 0) ? 128 : 256;
        we[i] = srcs[job][row * stride + kin];
    }
    if (cursor)
        for (int i = gid; i < NBUCK; i += gsz) cursor[i] = i * CAP;
}

// ---------------------------------------------------------------------------
// Bin edges by dst>>7 into per-bucket pair regions. Per block: LDS histogram
// over its CHUNK, ONE global atomic per nonzero bucket to reserve space
// (~153K atomics total vs 3.2M direct), then scattered 8B pair writes
// (L2/L3-absorbed; sage re-reads them while L3-hot).
// ---------------------------------------------------------------------------
__global__ __launch_bounds__(256) void bin_edges(const float* __restrict__ ef,
                                                 const int* __restrict__ dst,
                                                 int* __restrict__ cursor,
                                                 float2* __restrict__ pairs) {
    __shared__ int hist[NBUCK];
    __shared__ int base[NBUCK];
    const int start = blockIdx.x * CHUNK;
    const int end   = min(start + CHUNK, N_EDGES);
    for (int b = threadIdx.x; b < NBUCK; b += 256) hist[b] = 0;
    __syncthreads();
    for (int i = start + threadIdx.x * 4; i < end; i += 1024) {
        const int4 d = *(const int4*)&dst[i];
        atomicAdd(&hist[d.x >> 7], 1);
        atomicAdd(&hist[d.y >> 7], 1);
        atomicAdd(&hist[d.z >> 7], 1);
        atomicAdd(&hist[d.w >> 7], 1);
    }
    __syncthreads();
    for (int b = threadIdx.x; b < NBUCK; b += 256) {
        const int c = hist[b];
        base[b] = (c > 0) ? atomicAdd(&cursor[b], c) : 0;
        hist[b] = 0;
    }
    __syncthreads();
    for (int i = start + threadIdx.x * 4; i < end; i += 1024) {
        const int4   d = *(const int4*)&dst[i];
        const float4 f = *(const float4*)&ef[i];
        int b0 = d.x >> 7; int s0 = base[b0] + atomicAdd(&hist[b0], 1);
        pairs[s0] = make_float2(f.x, __int_as_float(d.x));
        int b1 = d.y >> 7; int s1 = base[b1] + atomicAdd(&hist[b1], 1);
        pairs[s1] = make_float2(f.y, __int_as_float(d.y));
        int b2 = d.z >> 7; int s2 = base[b2] + atomicAdd(&hist[b2], 1);
        pairs[s2] = make_float2(f.z, __int_as_float(d.z));
        int b3 = d.w >> 7; int s3 = base[b3] + atomicAdd(&hist[b3], 1);
        pairs[s3] = make_float2(f.w, __int_as_float(d.w));
    }
}

// fallback: device-scope split-4 scatter (known-good)
__global__ void scatter4(const float4* __restrict__ ef4,
                         const int4* __restrict__ dst4,
                         float* __restrict__ e) {
    const int n4 = N_EDGES / 4;
    for (int i = blockIdx.x * blockDim.x + threadIdx.x; i < n4;
         i += gridDim.x * blockDim.x) {
        const float4 f = ef4[i];
        const int4   d = dst4[i];
        atomicAdd(&e[d.x], f.x);
        atomicAdd(&e[SH_STRIDE + d.y], f.y);
        atomicAdd(&e[2 * SH_STRIDE + d.z], f.z);
        atomicAdd(&e[3 * SH_STRIDE + d.w], f.w);
    }
}

// ---------------------------------------------------------------------------
// One layer over a 128-node tile (R3 config: wave owns 64 cols x 128 nodes,
// jt4 x mt8, a-frag prefetched one k-step ahead from global/L2; b-frag from
// LDS ds_read_b128). D: col=lane&15 -> node, row=quad*4+r -> 4 consecutive
// output features -> packed 8B LDS stores.
// ---------------------------------------------------------------------------
template<int K>
__device__ __forceinline__ void layer_mm(const _Float16* __restrict__ Wl,
                                         _Float16 (* __restrict__ Hs)[264],
                                         const float* __restrict__ es,
                                         const float* __restrict__ wes,
                                         const float* __restrict__ bs,
                                         int wave, int m_, int quad) {
    f32x4 acc[4][8];
    #pragma unroll
    for (int jt = 0; jt < 4; ++jt)
        #pragma unroll
        for (int mt = 0; mt < 8; ++mt)
            acc[jt][mt] = (f32x4){0.f, 0.f, 0.f, 0.f};

    const _Float16* __restrict__ wp = Wl + (size_t)(wave * 64 + m_) * K + quad * 8;

    half8 a[4];
    #pragma unroll
    for (int jt = 0; jt < 4; ++jt)
        a[jt] = *(const half8*)(wp + jt * 16 * K);

    #pragma unroll
    for (int kk = 0; kk < K; kk += 32) {
        half8 a2[4];
        if (kk + 32 < K) {
            #pragma unroll
            for (int jt = 0; jt < 4; ++jt)
                a2[jt] = *(const half8*)(wp + jt * 16 * K + kk + 32);
        }
        half8 b[8];
        #pragma unroll
        for (int mt = 0; mt < 8; ++mt)
            b[mt] = *(const half8*)&Hs[mt * 16 + m_][kk + quad * 8];
        #pragma unroll
        for (int jt = 0; jt < 4; ++jt)
            #pragma unroll
            for (int mt = 0; mt < 8; ++mt)
                acc[jt][mt] = __builtin_amdgcn_mfma_f32_16x16x32_f16(
                    a[jt], b[mt], acc[jt][mt], 0, 0, 0);
        if (kk + 32 < K) {
            #pragma unroll
            for (int jt = 0; jt < 4; ++jt) a[jt] = a2[jt];
        }
    }
    __syncthreads();   // all waves done reading Hs; wes/bs ready

    #pragma unroll
    for (int jt = 0; jt < 4; ++jt) {
        const int jbase = wave * 64 + jt * 16 + quad * 4;
        const float4 we4 = *(const float4*)&wes[jbase];
        const float4 bb4 = *(const float4*)&bs[jbase];
        #pragma unroll
        for (int mt = 0; mt < 8; ++mt) {
            const int node = mt * 16 + m_;
            const float ev = es[node];
            half4v h;
            h[0] = (_Float16)fmaxf(acc[jt][mt][0] + ev * we4.x + bb4.x, 0.f);
            h[1] = (_Float16)fmaxf(acc[jt][mt][1] + ev * we4.y + bb4.y, 0.f);
            h[2] = (_Float16)fmaxf(acc[jt][mt][2] + ev * we4.z + bb4.z, 0.f);
            h[3] = (_Float16)fmaxf(acc[jt][mt][3] + ev * we4.w + bb4.w, 0.f);
            *(half4v*)&Hs[node][jbase] = h;
        }
    }
    __syncthreads();   // Hs complete before next layer / wes overwrite
}

// ---------------------------------------------------------------------------
__global__ __launch_bounds__(256) void sage_fused(
    const float* __restrict__ node_feat,
    const int* __restrict__ cursor, const float2* __restrict__ pairs,
    const float* __restrict__ esh, int nsh,
    const _Float16* __restrict__ Wpack, const float* __restrict__ wepack,
    const float* __restrict__ b1, const float* __restrict__ bm1,
    const float* __restrict__ bm2, const float* __restrict__ bm3,
    const float* __restrict__ bm4, const float* __restrict__ br1,
    const float* __restrict__ br2, const float* __restrict__ wr3,
    const float* __restrict__ br3, float* __restrict__ out) {

    __shared__ _Float16 Hs[128][264];   // +8-half pad
    __shared__ float es[128];
    __shared__ float wes[256];
    __shared__ float bs[256];
    __shared__ float red[2][128];

    const int tid  = threadIdx.x;
    const int wave = tid >> 6;
    const int lane = tid & 63;
    const int m_   = lane & 15;
    const int quad = lane >> 4;
    const int node0 = blockIdx.x * 128;

    if (tid < 128) es[tid] = 0.f;
    __syncthreads();

    // ---- stage node_feat tile (fp32 -> fp16), cols [0,128) ----
    for (int idx = tid; idx < 128 * 16; idx += 256) {
        const int row = idx >> 4, g = idx & 15;
        int node = node0 + row; if (node >= N_NODES) node = N_NODES - 1;
        const float4* src = (const float4*)(node_feat + (size_t)node * 128 + g * 8);
        const float4 v0 = src[0], v1 = src[1];
        half8 h;
        h[0] = (_Float16)v0.x; h[1] = (_Float16)v0.y;
        h[2] = (_Float16)v0.z; h[3] = (_Float16)v0.w;
        h[4] = (_Float16)v1.x; h[5] = (_Float16)v1.y;
        h[6] = (_Float16)v1.z; h[7] = (_Float16)v1.w;
        *(half8*)&Hs[row][g * 8] = h;
    }
    // ---- edge aggregate for this tile ----
    if (nsh == 0) {
        const int cnt = cursor[blockIdx.x] - blockIdx.x * CAP;
        const float2* __restrict__ pp = pairs + (size_t)blockIdx.x * CAP;
        for (int i = tid; i < cnt; i += 256) {
            const float2 p = pp[i];
            atomicAdd(&es[__float_as_int(p.y) & 127], p.x);
        }
    } else if (tid < 128) {
        int node = node0 + tid; if (node >= N_NODES) node = N_NODES - 1;
        float s = 0.f;
        for (int sh = 0; sh < nsh; ++sh) s += esh[(size_t)sh * SH_STRIDE + node];
        es[tid] = s;
    }
    __syncthreads();

    const float* b_l[7] = {b1, bm1, bm2, bm3, bm4, br1, br2};

    // layer 0: K=128
    wes[tid] = wepack[tid];
    bs[tid]  = b1[tid];
    layer_mm<128>(Wpack, Hs, es, wes, bs, wave, m_, quad);

    // layers 1..6: K=256
    for (int l = 1; l < 7; ++l) {
        wes[tid] = (l < 6) ? wepack[l * 256 + tid] : 0.f;
        bs[tid]  = b_l[l][tid];
        layer_mm<256>(Wpack + 32768 + (l - 1) * 65536, Hs, es, wes, bs,
                      wave, m_, quad);
    }

    // ---- final 256 -> 1 dot (fp32) ----
    wes[tid] = wr3[tid];
    __syncthreads();
    {
        const int row = tid & 127, seg = tid >> 7;
        const _Float16* hp = &Hs[row][seg * 128];
        const float* wp = &wes[seg * 128];
        float s = 0.f;
        #pragma unroll 8
        for (int k = 0; k < 128; ++k) s += (float)hp[k] * wp[k];
        red[seg][row] = s;
    }
    __syncthreads();
    if (tid < 128) {
        const int node = node0 + tid;
        if (node < N_NODES)
            out[node] = red[0][tid] + red[1][tid] + br3[0];
    }
}

// ---------------------------------------------------------------------------
extern "C" void kernel_launch(void* const* d_in, const int* in_sizes, int n_in,
                              void* d_out, int out_size, void* d_ws,
                              size_t ws_size, hipStream_t stream) {
    const float* node_feat = (const float*)d_in[0];
    const float* edge_feat = (const float*)d_in[1];
    const int*   edge_dst  = (const int*)d_in[2];
    const float* W1  = (const float*)d_in[3];  const float* b1  = (const float*)d_in[4];
    const float* Wm1 = (const float*)d_in[5];  const float* bm1 = (const float*)d_in[6];
    const float* Wm2 = (const float*)d_in[7];  const float* bm2 = (const float*)d_in[8];
    const float* Wm3 = (const float*)d_in[9];  const float* bm3 = (const float*)d_in[10];
    const float* Wm4 = (const float*)d_in[11]; const float* bm4 = (const float*)d_in[12];
    const float* Wr1 = (const float*)d_in[13]; const float* br1 = (const float*)d_in[14];
    const float* Wr2 = (const float*)d_in[15]; const float* br2 = (const float*)d_in[16];
    const float* Wr3 = (const float*)d_in[17]; const float* br3 = (const float*)d_in[18];
    float* out = (float*)d_out;

    // workspace layout: Wp | wep | cursor | pairs (or fallback shadows)
    char* ws = (char*)d_ws;
    _Float16* Wp     = (_Float16*)ws;                      // 851968 B
    float*    wep    = (float*)(ws + 851968);              // 6144 B
    int*      cursor = (int*)(ws + 858112);                // 4096 B (NBUCK ints)
    float2*   pairs  = (float2*)(ws + 862208);             // NBUCK*CAP*8 B
    float*    esh    = (float*)(ws + 862208);              // fallback shadows

    const size_t need_bins = 862208 + (size_t)NBUCK * CAP * 8;   // ~32.9 MB
    const bool use_bins = (ws_size >= need_bins);

    if (use_bins) {
        pack_all<<<1664, 256, 0, stream>>>(W1, Wm1, Wm2, Wm3, Wm4, Wr1, Wr2,
                                           Wp, wep, cursor);
        const int nbin = (N_EDGES + CHUNK - 1) / CHUNK;   // 196
        bin_edges<<<nbin, 256, 0, stream>>>(edge_feat, edge_dst, cursor, pairs);
        const int nblk = (N_NODES + 127) / 128;   // 782
        sage_fused<<<nblk, 256, 0, stream>>>(node_feat, cursor, pairs,
                                             nullptr, 0, Wp, wep,
                                             b1, bm1, bm2, bm3, bm4, br1, br2,
                                             Wr3, br3, out);
    } else {
        pack_all<<<1664, 256, 0, stream>>>(W1, Wm1, Wm2, Wm3, Wm4, Wr1, Wr2,
                                           Wp, wep, nullptr);
        hipMemsetAsync(esh, 0, (size_t)4 * SH_STRIDE * 4, stream);
        scatter4<<<3125, 256, 0, stream>>>((const float4*)edge_feat,
                                           (const int4*)edge_dst, esh);
        const int nblk = (N_NODES + 127) / 128;   // 782
        sage_fused<<<nblk, 256, 0, stream>>>(node_feat, nullptr, nullptr,
                                             esh, 4, Wp, wep,
                                             b1, bm1, bm2, bm3, bm4, br1, br2,
                                             Wr3, br3, out);
    }
}